// Round 1
// baseline (700.340 us; speedup 1.0000x reference)
//
#include <hip/hip_runtime.h>

// Conv3d(8->32, k=3, VALID) + bias + HardSwish + GroupNorm(4) + global mean pool.
// Fused: never materialize conv output. Kernel A computes per-(b,c) sums of
// hardswish(conv) and its square; kernel B does the GroupNorm algebra on 512 values.

#define CI 8
#define CO 32
#define IN 48
#define OUTD 46
#define TD 4
#define TH 4
#define TW 16
#define XROW (TW + 4)   // 20 floats: 16B-aligned row stride, room for +2 halo

// threads: tco(4) x tw(2) x th(4) x td(4) = 128
__global__ __launch_bounds__(128) void conv_hs_partial(
    const float* __restrict__ x, const float* __restrict__ w,
    const float* __restrict__ bias, float* __restrict__ ws1, float* __restrict__ ws2)
{
    __shared__ __align__(16) float wlds[CI * 27 * CO];              // [ci][kd][kh][kw][co]
    __shared__ __align__(16) float xlds[CI][TD + 2][TH + 2][XROW];  // 5760 floats
    __shared__ float s1b[CO];
    __shared__ float s2b[CO];

    int blk = blockIdx.x;
    int bw = blk % 3;
    int bh = (blk / 3) % 12;
    int bd = (blk / 36) % 12;
    int b  = blk / 432;

    int tid = threadIdx.x;
    int tco = tid & 3;
    int tw  = (tid >> 2) & 1;
    int th  = (tid >> 3) & 3;
    int td  = (tid >> 5) & 3;

    if (tid < CO) { s1b[tid] = 0.f; s2b[tid] = 0.f; }

    // Stage weights into LDS, reordered to [ci][kd][kh][kw][co] so the inner
    // 8-channel read is contiguous (2x ds_read_b128, tco-offset bank-aligned).
    for (int idx = tid; idx < CI * 27 * CO; idx += 128) {
        int co = idx & 31;
        int q  = idx >> 5;
        int kw = q % 3; q /= 3;
        int kh = q % 3; q /= 3;
        int kd = q % 3;
        int ci = q / 3;
        wlds[idx] = w[(((co * CI + ci) * 3 + kd) * 3 + kh) * 3 + kw];
    }

    // Stage x tile (with +2 halo per dim); clamp OOB indices — clamped values
    // only ever feed masked-out (invalid) outputs.
    int zd0 = bd * TD, yh0 = bh * TH, xw0 = bw * TW;
    for (int idx = tid; idx < CI * (TD + 2) * (TH + 2) * XROW; idx += 128) {
        int dx = idx % XROW;
        int q  = idx / XROW;
        int yy = q % (TH + 2); q /= (TH + 2);
        int zz = q % (TD + 2);
        int ci = q / (TD + 2);
        int gx = min(xw0 + dx, IN - 1);
        int gy = min(yh0 + yy, IN - 1);
        int gz = min(zd0 + zz, IN - 1);
        xlds[ci][zz][yy][dx] = x[(((b * CI + ci) * IN + gz) * IN + gy) * IN + gx];
    }
    __syncthreads();

    // Register block: 8 consecutive w-positions x 8 output channels per thread.
    float acc[8][8];
    #pragma unroll
    for (int c = 0; c < 8; ++c)
        #pragma unroll
        for (int i = 0; i < 8; ++i)
            acc[c][i] = 0.f;

    int wb = tw * 8;
    for (int ci = 0; ci < CI; ++ci) {
        #pragma unroll
        for (int kd = 0; kd < 3; ++kd) {
            #pragma unroll
            for (int kh = 0; kh < 3; ++kh) {
                float xr[10];
                #pragma unroll
                for (int i = 0; i < 10; ++i)
                    xr[i] = xlds[ci][td + kd][th + kh][wb + i];
                const float* wp = &wlds[((ci * 9 + kd * 3 + kh) * 3) * CO + tco * 8];
                #pragma unroll
                for (int kw = 0; kw < 3; ++kw) {
                    float wv[8];
                    #pragma unroll
                    for (int c = 0; c < 8; ++c) wv[c] = wp[kw * CO + c];
                    #pragma unroll
                    for (int c = 0; c < 8; ++c)
                        #pragma unroll
                        for (int i = 0; i < 8; ++i)
                            acc[c][i] = fmaf(xr[i + kw], wv[c], acc[c][i]);
                }
            }
        }
    }

    // Epilogue: bias + hardswish, accumulate valid positions into per-channel sums.
    int ho = yh0 + th;
    int dd = zd0 + td;
    int wg0 = xw0 + wb;
    if (ho < OUTD && dd < OUTD) {
        #pragma unroll
        for (int c = 0; c < 8; ++c) {
            int cg = tco * 8 + c;
            float bv = bias[cg];
            float t1 = 0.f, t2 = 0.f;
            #pragma unroll
            for (int i = 0; i < 8; ++i) {
                if (wg0 + i < OUTD) {
                    float v = acc[c][i] + bv;
                    float u = fminf(fmaxf(v + 3.0f, 0.0f), 6.0f);
                    float hs = v * u * (1.0f / 6.0f);
                    t1 += hs;
                    t2 += hs * hs;
                }
            }
            atomicAdd(&s1b[cg], t1);
            atomicAdd(&s2b[cg], t2);
        }
    }
    __syncthreads();
    if (tid < CO)           atomicAdd(&ws1[b * CO + tid], s1b[tid]);
    else if (tid < 2 * CO)  atomicAdd(&ws2[b * CO + (tid - CO)], s2b[tid - CO]);
}

// 512 threads: one per (b, c). Group = 8 contiguous channels = 8 contiguous lanes.
__global__ __launch_bounds__(512) void gn_finalize(
    const float* __restrict__ ws1, const float* __restrict__ ws2,
    const float* __restrict__ gnw, const float* __restrict__ gnb,
    float* __restrict__ out)
{
    int tid = threadIdx.x;
    int c = tid & 31;
    float s1 = ws1[tid], s2 = ws2[tid];
    float g1 = s1, g2 = s2;
    #pragma unroll
    for (int k = 1; k < 8; k <<= 1) {
        g1 += __shfl_xor(g1, k, 64);
        g2 += __shfl_xor(g2, k, 64);
    }
    const float Nsp  = 46.0f * 46.0f * 46.0f;   // 97336
    const float invN = 1.0f / (8.0f * Nsp);
    float mean = g1 * invN;
    float var  = fmaxf(g2 * invN - mean * mean, 0.0f);
    float rstd = rsqrtf(var + 1e-5f);
    float mc   = s1 * (1.0f / Nsp);
    out[tid] = (mc - mean) * rstd * gnw[c] + gnb[c];
}

extern "C" void kernel_launch(void* const* d_in, const int* in_sizes, int n_in,
                              void* d_out, int out_size, void* d_ws, size_t ws_size,
                              hipStream_t stream) {
    const float* x    = (const float*)d_in[0];
    const float* w    = (const float*)d_in[1];
    const float* bias = (const float*)d_in[2];
    const float* gnw  = (const float*)d_in[3];
    const float* gnb  = (const float*)d_in[4];
    float* out = (float*)d_out;
    float* ws1 = (float*)d_ws;
    float* ws2 = ws1 + 512;

    hipMemsetAsync(d_ws, 0, 1024 * sizeof(float), stream);
    conv_hs_partial<<<dim3(16 * 3 * 12 * 12), dim3(128), 0, stream>>>(x, w, bias, ws1, ws2);
    gn_finalize<<<dim3(1), dim3(512), 0, stream>>>(ws1, ws2, gnw, gnb, out);
}

// Round 2
// 434.172 us; speedup vs baseline: 1.6130x; 1.6130x over previous
//
#include <hip/hip_runtime.h>

// Conv3d(8->32, k=3, VALID) + bias + HardSwish + GroupNorm(4) + global mean pool.
// Fused: never materialize conv output. Kernel A computes per-(b,c) sums of
// hardswish(conv) and its square; kernel B does the GroupNorm algebra on 512 values.
//
// R1: 256-thread blocks (4 waves), each thread computes 4 co x 8 w positions.
// Same 51.2 KB LDS tile -> 3 blocks/CU but 12 waves/CU (was 6). Latency-bound fix.

#define CI 8
#define CO 32
#define IN 48
#define OUTD 46
#define TD 4
#define TH 4
#define TW 16
#define XROW (TW + 4)   // 20 floats: 80 B row stride (16B-aligned), room for +2 halo

// threads: tco(8) x tw(2) x th(4) x td(4) = 256
__global__ __launch_bounds__(256, 3) void conv_hs_partial(
    const float* __restrict__ x, const float* __restrict__ w,
    const float* __restrict__ bias, float* __restrict__ ws1, float* __restrict__ ws2)
{
    __shared__ __align__(16) float wlds[CI * 27 * CO];              // [ci][kd][kh][kw][co]
    __shared__ __align__(16) float xlds[CI][TD + 2][TH + 2][XROW];  // 5760 floats
    __shared__ float s1b[CO];
    __shared__ float s2b[CO];

    int blk = blockIdx.x;
    int bw = blk % 3;
    int bh = (blk / 3) % 12;
    int bd = (blk / 36) % 12;
    int b  = blk / 432;

    int tid = threadIdx.x;
    int tco = tid & 7;          // 8 co-groups of 4 channels
    int tw  = (tid >> 3) & 1;
    int th  = (tid >> 4) & 3;
    int td  = (tid >> 6) & 3;

    if (tid < CO) { s1b[tid] = 0.f; s2b[tid] = 0.f; }

    // Stage weights, reordered to [ci][kd][kh][kw][co]: per-thread inner read is
    // 4 contiguous floats at a 16B-aligned offset (ds_read_b128), tco-spread.
    for (int idx = tid; idx < CI * 27 * CO; idx += 256) {
        int co = idx & 31;
        int q  = idx >> 5;
        int kw = q % 3; q /= 3;
        int kh = q % 3; q /= 3;
        int kd = q % 3;
        int ci = q / 3;
        wlds[idx] = w[(((co * CI + ci) * 3 + kd) * 3 + kh) * 3 + kw];
    }

    // Stage x tile (+2 halo per dim); clamp OOB — clamped values only feed
    // masked-out (invalid) outputs.
    int zd0 = bd * TD, yh0 = bh * TH, xw0 = bw * TW;
    for (int idx = tid; idx < CI * (TD + 2) * (TH + 2) * XROW; idx += 256) {
        int dx = idx % XROW;
        int q  = idx / XROW;
        int yy = q % (TH + 2); q /= (TH + 2);
        int zz = q % (TD + 2);
        int ci = q / (TD + 2);
        int gx = min(xw0 + dx, IN - 1);
        int gy = min(yh0 + yy, IN - 1);
        int gz = min(zd0 + zz, IN - 1);
        xlds[ci][zz][yy][dx] = x[(((b * CI + ci) * IN + gz) * IN + gy) * IN + gx];
    }
    __syncthreads();

    // Register block: 4 output channels x 8 consecutive w-positions per thread.
    float acc[4][8];
    #pragma unroll
    for (int c = 0; c < 4; ++c)
        #pragma unroll
        for (int i = 0; i < 8; ++i)
            acc[c][i] = 0.f;

    int wb = tw * 8;
    for (int ci = 0; ci < CI; ++ci) {
        #pragma unroll
        for (int kd = 0; kd < 3; ++kd) {
            #pragma unroll
            for (int kh = 0; kh < 3; ++kh) {
                float xr[10];
                #pragma unroll
                for (int i = 0; i < 10; ++i)
                    xr[i] = xlds[ci][td + kd][th + kh][wb + i];
                const float* wp = &wlds[((ci * 9 + kd * 3 + kh) * 3) * CO + tco * 4];
                #pragma unroll
                for (int kw = 0; kw < 3; ++kw) {
                    float wv[4];
                    #pragma unroll
                    for (int c = 0; c < 4; ++c) wv[c] = wp[kw * CO + c];
                    #pragma unroll
                    for (int c = 0; c < 4; ++c)
                        #pragma unroll
                        for (int i = 0; i < 8; ++i)
                            acc[c][i] = fmaf(xr[i + kw], wv[c], acc[c][i]);
                }
            }
        }
    }

    // Epilogue: bias + hardswish -> per-channel S1/S2. Predicated (no divergent
    // branch around shuffles); 8-lane shfl pre-reduction over the lanes sharing
    // the same co-group (bits 3..5 of tid within a wave) -> 8x fewer LDS atomics.
    int ho  = yh0 + th;
    int dd  = zd0 + td;
    int wg0 = xw0 + wb;
    bool rowok = (ho < OUTD) && (dd < OUTD);
    #pragma unroll
    for (int c = 0; c < 4; ++c) {
        int cg = tco * 4 + c;
        float bv = bias[cg];
        float t1 = 0.f, t2 = 0.f;
        #pragma unroll
        for (int i = 0; i < 8; ++i) {
            float v = acc[c][i] + bv;
            float u = fminf(fmaxf(v + 3.0f, 0.0f), 6.0f);
            float hs = v * u * (1.0f / 6.0f);
            bool ok = rowok && (wg0 + i < OUTD);
            t1 += ok ? hs : 0.f;
            t2 += ok ? hs * hs : 0.f;
        }
        #pragma unroll
        for (int k = 8; k < 64; k <<= 1) {
            t1 += __shfl_xor(t1, k, 64);
            t2 += __shfl_xor(t2, k, 64);
        }
        if ((tid & 56) == 0) {
            atomicAdd(&s1b[cg], t1);
            atomicAdd(&s2b[cg], t2);
        }
    }
    __syncthreads();
    if (tid < CO)           atomicAdd(&ws1[b * CO + tid], s1b[tid]);
    else if (tid < 2 * CO)  atomicAdd(&ws2[b * CO + (tid - CO)], s2b[tid - CO]);
}

// 512 threads: one per (b, c). Group = 8 contiguous channels = 8 contiguous lanes.
__global__ __launch_bounds__(512) void gn_finalize(
    const float* __restrict__ ws1, const float* __restrict__ ws2,
    const float* __restrict__ gnw, const float* __restrict__ gnb,
    float* __restrict__ out)
{
    int tid = threadIdx.x;
    int c = tid & 31;
    float s1 = ws1[tid], s2 = ws2[tid];
    float g1 = s1, g2 = s2;
    #pragma unroll
    for (int k = 1; k < 8; k <<= 1) {
        g1 += __shfl_xor(g1, k, 64);
        g2 += __shfl_xor(g2, k, 64);
    }
    const float Nsp  = 46.0f * 46.0f * 46.0f;   // 97336
    const float invN = 1.0f / (8.0f * Nsp);
    float mean = g1 * invN;
    float var  = fmaxf(g2 * invN - mean * mean, 0.0f);
    float rstd = rsqrtf(var + 1e-5f);
    float mc   = s1 * (1.0f / Nsp);
    out[tid] = (mc - mean) * rstd * gnw[c] + gnb[c];
}

extern "C" void kernel_launch(void* const* d_in, const int* in_sizes, int n_in,
                              void* d_out, int out_size, void* d_ws, size_t ws_size,
                              hipStream_t stream) {
    const float* x    = (const float*)d_in[0];
    const float* w    = (const float*)d_in[1];
    const float* bias = (const float*)d_in[2];
    const float* gnw  = (const float*)d_in[3];
    const float* gnb  = (const float*)d_in[4];
    float* out = (float*)d_out;
    float* ws1 = (float*)d_ws;
    float* ws2 = ws1 + 512;

    hipMemsetAsync(d_ws, 0, 1024 * sizeof(float), stream);
    conv_hs_partial<<<dim3(16 * 3 * 12 * 12), dim3(256), 0, stream>>>(x, w, bias, ws1, ws2);
    gn_finalize<<<dim3(1), dim3(512), 0, stream>>>(ws1, ws2, gnw, gnb, out);
}

// Round 3
// 244.840 us; speedup vs baseline: 2.8604x; 1.7733x over previous
//
#include <hip/hip_runtime.h>

// Conv3d(8->32, k=3, VALID) + bias + HardSwish + GroupNorm(4) + mean pool.
// R2: MFMA implicit GEMM. Per (b,z,y,nt16): D[co,16xcols] = sum over 9 chunks
// (kd,kh) of A[co, k=4*ci+kw] * B[k, col], kw padded to 4 with ZERO WEIGHT so
// B's 4th slot is don't-care -> B frag = 4 consecutive x elems per ci (unaligned
// LDS window via funnel shift). Weights split bf16 hi+lo (w exact to ~2^-18);
// x single bf16 (random error averages out in the 97336-elem pooling).

#define CI 8
#define CO 32
#define IN 48
#define OUTD 46

// LDS x-tile geometry: [ci][zr 0..5][yr 0..5][x 0..51], row stride 52 elems
// (104 B, fits b96 window at e<=46), ci stride 1880 elems (+8 pad: 940 dwords
// = 12 mod 32 banks -> quads land on banks 0/12/24/4, no systematic conflict).
#define ROWE 52
#define CISTRIDE 1880

typedef short v8s  __attribute__((ext_vector_type(8)));
typedef float f32x4 __attribute__((ext_vector_type(4)));
typedef int   i32x4 __attribute__((ext_vector_type(4)));

__device__ __forceinline__ unsigned short f2bf(float f) {
    unsigned u = __builtin_bit_cast(unsigned, f);
    return (unsigned short)((u + 0x7fffu + ((u >> 16) & 1u)) >> 16);   // RNE
}
__device__ __forceinline__ float bf2f(unsigned short h) {
    unsigned u = ((unsigned)h) << 16;
    return __builtin_bit_cast(float, u);
}

__global__ __launch_bounds__(256, 2) void conv_hs_mfma(
    const float* __restrict__ x, const float* __restrict__ w,
    const float* __restrict__ bias, float* __restrict__ ws1, float* __restrict__ ws2)
{
    __shared__ unsigned short xlds[CI * CISTRIDE];   // 30.1 KB
    __shared__ float s1b[CO], s2b[CO];

    const int tid  = threadIdx.x;
    const int lane = tid & 63;
    const int wv   = tid >> 6;          // wave id: its z offset
    const int n    = lane & 15;         // MFMA row (A) / col (B) index
    const int q    = lane >> 4;         // k-octet: ci pair {2q, 2q+1}

    const int blk = blockIdx.x;
    const int b   = blk / 144;
    const int r0  = blk - b * 144;
    const int zb  = r0 / 12;
    const int yb  = r0 - zb * 12;
    const int z0  = zb * 4, y0 = yb * 4;
    const int z   = z0 + wv;

    // ---- A fragments: weights, hi+lo bf16, zero-padded at kw=3. In registers.
    v8s Ah[2][9], Al[2][9];
    #pragma unroll
    for (int h = 0; h < 2; ++h) {
        const int co = h * 16 + n;
        #pragma unroll
        for (int kd = 0; kd < 3; ++kd) {
            #pragma unroll
            for (int kh = 0; kh < 3; ++kh) {
                int ihv[4], ilv[4];
                #pragma unroll
                for (int cs = 0; cs < 2; ++cs) {
                    const int ci = 2 * q + cs;
                    const float* wp = w + (((co * CI + ci) * 3 + kd) * 3 + kh) * 3;
                    float w0 = wp[0], w1 = wp[1], w2 = wp[2];
                    unsigned short h0 = f2bf(w0), h1 = f2bf(w1), h2 = f2bf(w2);
                    unsigned short l0 = f2bf(w0 - bf2f(h0));
                    unsigned short l1 = f2bf(w1 - bf2f(h1));
                    unsigned short l2 = f2bf(w2 - bf2f(h2));
                    ihv[cs * 2 + 0] = (int)(((unsigned)h1 << 16) | h0);
                    ihv[cs * 2 + 1] = (int)(unsigned)h2;      // kw=3 slot = 0
                    ilv[cs * 2 + 0] = (int)(((unsigned)l1 << 16) | l0);
                    ilv[cs * 2 + 1] = (int)(unsigned)l2;
                }
                Ah[h][kd * 3 + kh] = __builtin_bit_cast(v8s, (i32x4){ihv[0], ihv[1], ihv[2], ihv[3]});
                Al[h][kd * 3 + kh] = __builtin_bit_cast(v8s, (i32x4){ilv[0], ilv[1], ilv[2], ilv[3]});
            }
        }
    }

    float bias_r[8];
    #pragma unroll
    for (int h = 0; h < 2; ++h)
        #pragma unroll
        for (int i = 0; i < 4; ++i)
            bias_r[h * 4 + i] = bias[h * 16 + q * 4 + i];

    if (tid < CO) { s1b[tid] = 0.f; s2b[tid] = 0.f; }

    // ---- stage x tile -> LDS bf16 (clamped OOB feeds only masked outputs) ----
    for (int idx = tid; idx < CI * 36 * ROWE; idx += 256) {
        int ci = idx / (36 * ROWE);
        int r  = idx - ci * (36 * ROWE);
        int zy = r / ROWE;
        int xx = r - zy * ROWE;
        int zr = zy / 6;
        int yr = zy - zr * 6;
        int gz = min(z0 + zr, IN - 1);
        int gy = min(y0 + yr, IN - 1);
        int gx = min(xx, IN - 1);
        float v = x[(((b * CI + ci) * IN + gz) * IN + gy) * IN + gx];
        xlds[ci * CISTRIDE + zy * ROWE + xx] = f2bf(v);
    }
    __syncthreads();

    float t1[8] = {0, 0, 0, 0, 0, 0, 0, 0};
    float t2[8] = {0, 0, 0, 0, 0, 0, 0, 0};

    if (z < OUTD) {
        for (int y = 0; y < 4; ++y) {
            if (y0 + y >= OUTD) break;                 // wave-uniform
            #pragma unroll
            for (int nt = 0; nt < 3; ++nt) {
                const int col = nt * 16 + n;
                const int e2  = (col & ~1) * 2;        // byte offset of aligned window
                const int sh  = (col & 1) * 16;        // funnel shift for odd cols
                const char* base = (const char*)xlds + q * (2 * CISTRIDE * 2) + e2;
                f32x4 a00 = {0, 0, 0, 0}, a01 = {0, 0, 0, 0};
                f32x4 a10 = {0, 0, 0, 0}, a11 = {0, 0, 0, 0};
                #pragma unroll
                for (int kd = 0; kd < 3; ++kd) {
                    #pragma unroll
                    for (int kh = 0; kh < 3; ++kh) {
                        const int ch = kd * 3 + kh;
                        const unsigned* p0 = (const unsigned*)(base + ((wv + kd) * 6 + (y + kh)) * (ROWE * 2));
                        const unsigned* p1 = (const unsigned*)((const char*)p0 + CISTRIDE * 2);
                        unsigned d0 = p0[0], d1 = p0[1], d2 = p0[2];
                        unsigned g0 = p1[0], g1 = p1[1], g2 = p1[2];
                        unsigned b0 = (unsigned)((((unsigned long long)d1 << 32) | d0) >> sh);
                        unsigned b1 = (unsigned)((((unsigned long long)d2 << 32) | d1) >> sh);
                        unsigned b2 = (unsigned)((((unsigned long long)g1 << 32) | g0) >> sh);
                        unsigned b3 = (unsigned)((((unsigned long long)g2 << 32) | g1) >> sh);
                        v8s B = __builtin_bit_cast(v8s, (i32x4){(int)b0, (int)b1, (int)b2, (int)b3});
                        a00 = __builtin_amdgcn_mfma_f32_16x16x32_bf16(Ah[0][ch], B, a00, 0, 0, 0);
                        a10 = __builtin_amdgcn_mfma_f32_16x16x32_bf16(Ah[1][ch], B, a10, 0, 0, 0);
                        a01 = __builtin_amdgcn_mfma_f32_16x16x32_bf16(Al[0][ch], B, a01, 0, 0, 0);
                        a11 = __builtin_amdgcn_mfma_f32_16x16x32_bf16(Al[1][ch], B, a11, 0, 0, 0);
                    }
                }
                const bool cok = col < OUTD;
                #pragma unroll
                for (int h = 0; h < 2; ++h) {
                    #pragma unroll
                    for (int i = 0; i < 4; ++i) {
                        float v = (h ? (a10[i] + a11[i]) : (a00[i] + a01[i])) + bias_r[h * 4 + i];
                        float uu = fminf(fmaxf(v + 3.0f, 0.0f), 6.0f);
                        float hs = v * uu * (1.0f / 6.0f);
                        t1[h * 4 + i] += cok ? hs : 0.f;
                        t2[h * 4 + i] += cok ? hs * hs : 0.f;
                    }
                }
            }
        }
    }

    // ---- reduce: over the 16 col-lanes within each quad (co sets are per-quad)
    #pragma unroll
    for (int j = 0; j < 8; ++j) {
        #pragma unroll
        for (int k = 1; k < 16; k <<= 1) {
            t1[j] += __shfl_xor(t1[j], k, 64);
            t2[j] += __shfl_xor(t2[j], k, 64);
        }
    }
    if (n == 0) {
        #pragma unroll
        for (int h = 0; h < 2; ++h)
            #pragma unroll
            for (int i = 0; i < 4; ++i) {
                atomicAdd(&s1b[h * 16 + q * 4 + i], t1[h * 4 + i]);
                atomicAdd(&s2b[h * 16 + q * 4 + i], t2[h * 4 + i]);
            }
    }
    __syncthreads();
    if (tid < CO)           atomicAdd(&ws1[b * CO + tid], s1b[tid]);
    else if (tid < 2 * CO)  atomicAdd(&ws2[b * CO + (tid - CO)], s2b[tid - CO]);
}

__global__ __launch_bounds__(512) void gn_finalize(
    const float* __restrict__ ws1, const float* __restrict__ ws2,
    const float* __restrict__ gnw, const float* __restrict__ gnb,
    float* __restrict__ out)
{
    int tid = threadIdx.x;
    int c = tid & 31;
    float s1 = ws1[tid], s2 = ws2[tid];
    float g1 = s1, g2 = s2;
    #pragma unroll
    for (int k = 1; k < 8; k <<= 1) {
        g1 += __shfl_xor(g1, k, 64);
        g2 += __shfl_xor(g2, k, 64);
    }
    const float Nsp  = 46.0f * 46.0f * 46.0f;
    const float invN = 1.0f / (8.0f * Nsp);
    float mean = g1 * invN;
    float var  = fmaxf(g2 * invN - mean * mean, 0.0f);
    float rstd = rsqrtf(var + 1e-5f);
    float mc   = s1 * (1.0f / Nsp);
    out[tid] = (mc - mean) * rstd * gnw[c] + gnb[c];
}

extern "C" void kernel_launch(void* const* d_in, const int* in_sizes, int n_in,
                              void* d_out, int out_size, void* d_ws, size_t ws_size,
                              hipStream_t stream) {
    const float* x    = (const float*)d_in[0];
    const float* w    = (const float*)d_in[1];
    const float* bias = (const float*)d_in[2];
    const float* gnw  = (const float*)d_in[3];
    const float* gnb  = (const float*)d_in[4];
    float* out = (float*)d_out;
    float* ws1 = (float*)d_ws;
    float* ws2 = ws1 + 512;

    hipMemsetAsync(d_ws, 0, 1024 * sizeof(float), stream);
    conv_hs_mfma<<<dim3(16 * 12 * 12), dim3(256), 0, stream>>>(x, w, bias, ws1, ws2);
    gn_finalize<<<dim3(1), dim3(512), 0, stream>>>(ws1, ws2, gnw, gnb, out);
}

// Round 4
// 157.962 us; speedup vs baseline: 4.4336x; 1.5500x over previous
//
#include <hip/hip_runtime.h>

// Conv3d(8->32, k=3, VALID) + bias + HardSwish + GroupNorm(4) + mean pool.
// R3: MFMA implicit GEMM, k-octet remap k = 8q + 2*kw + ci_parity so the
// B fragment is 4 stride-4 dwords from a ci-pair-packed LDS tile
// ([row][elem][q] dwords) -> two ds_read2_b32, no funnel shifts.
// A (hi+lo split bf16 weights) lives fully in registers (~200 VGPR, no spill,
// launch_bounds(256,2)). hi/lo chained into one accumulator per co-half.

#define IN 48
#define IN3 110592
#define OUTD 46
#define ROWDW 208          // 52 elems * 4 q-dwords per (zr,yr) row

typedef short v8s   __attribute__((ext_vector_type(8)));
typedef float f32x4 __attribute__((ext_vector_type(4)));
typedef int   i32x4 __attribute__((ext_vector_type(4)));

__device__ __forceinline__ unsigned short f2bf(float f) {
    unsigned u = __builtin_bit_cast(unsigned, f);
    return (unsigned short)((u + 0x7fffu + ((u >> 16) & 1u)) >> 16);   // RNE
}
__device__ __forceinline__ float bf2f(unsigned short h) {
    unsigned u = ((unsigned)h) << 16;
    return __builtin_bit_cast(float, u);
}

__global__ __launch_bounds__(256, 2) void conv_hs_mfma(
    const float* __restrict__ x, const float* __restrict__ w,
    const float* __restrict__ bias, float* __restrict__ ws1, float* __restrict__ ws2)
{
    __shared__ unsigned xdw[36 * ROWDW];     // 29.95 KB: [zr6][yr6][e52][q4]
    __shared__ float s1b[32], s2b[32];

    const int tid  = threadIdx.x;
    const int lane = tid & 63;
    const int wv   = tid >> 6;          // wave id = z offset within tile
    const int n    = lane & 15;         // MFMA A-row (co) / B-col index
    const int kq   = lane >> 4;         // k-octet: ci pair {2kq, 2kq+1}

    const int blk = blockIdx.x;
    const int b   = blk / 144;
    const int r0  = blk - b * 144;
    const int zb  = r0 / 12;
    const int yb  = r0 - zb * 12;
    const int z0  = zb * 4, y0 = yb * 4;
    const int z   = z0 + wv;

    if (tid < 32) { s1b[tid] = 0.f; s2b[tid] = 0.f; }

    // ---- A fragments (registers): k = 8*kq + 2*kw + c, c = ci parity.
    // dword j (=kw) of the frag = (lo: w[2kq][kw], hi: w[2kq+1][kw]); j=3 zero.
    v8s Ah[2][9], Al[2][9];
    #pragma unroll
    for (int h = 0; h < 2; ++h) {
        const int co = h * 16 + n;
        #pragma unroll
        for (int kd = 0; kd < 3; ++kd) {
            #pragma unroll
            for (int kh = 0; kh < 3; ++kh) {
                unsigned dh[4], dl[4];
                dh[3] = 0u; dl[3] = 0u;
                #pragma unroll
                for (int kw = 0; kw < 3; ++kw) {
                    const float w0 = w[(((co * 8 + 2 * kq)     * 3 + kd) * 3 + kh) * 3 + kw];
                    const float w1 = w[(((co * 8 + 2 * kq + 1) * 3 + kd) * 3 + kh) * 3 + kw];
                    unsigned short h0 = f2bf(w0), h1 = f2bf(w1);
                    unsigned short l0 = f2bf(w0 - bf2f(h0));
                    unsigned short l1 = f2bf(w1 - bf2f(h1));
                    dh[kw] = ((unsigned)h1 << 16) | h0;
                    dl[kw] = ((unsigned)l1 << 16) | l0;
                }
                Ah[h][kd * 3 + kh] = __builtin_bit_cast(v8s, (i32x4){(int)dh[0], (int)dh[1], (int)dh[2], (int)dh[3]});
                Al[h][kd * 3 + kh] = __builtin_bit_cast(v8s, (i32x4){(int)dl[0], (int)dl[1], (int)dl[2], (int)dl[3]});
            }
        }
    }

    // C/D layout: row(co) = 4*kq + i (+16h), col = n -> bias per (h,i)
    float bias_r[8];
    #pragma unroll
    for (int h = 0; h < 2; ++h)
        #pragma unroll
        for (int i = 0; i < 4; ++i)
            bias_r[h * 4 + i] = bias[h * 16 + kq * 4 + i];

    // ---- stage x tile: dword[(zr*6+yr)*208 + e*4 + q] = bf16(ci 2q+1)<<16 | bf16(ci 2q)
    {
        const int q = tid & 3;
        const int e = tid >> 2;            // 0..63, active e<52
        if (e < 52) {
            const int gx = min(e, IN - 1);
            const float* p0 = x + (b * 8 + 2 * q) * IN3 + gx;
            const float* p1 = p0 + IN3;
            #pragma unroll
            for (int zr = 0; zr < 6; ++zr) {
                const int gz = min(z0 + zr, IN - 1);
                #pragma unroll
                for (int yr = 0; yr < 6; ++yr) {
                    const int gy = min(y0 + yr, IN - 1);
                    const int off = gz * (IN * IN) + gy * IN;
                    float f0 = p0[off], f1 = p1[off];
                    unsigned pk = ((unsigned)f2bf(f1) << 16) | f2bf(f0);
                    xdw[(zr * 6 + yr) * ROWDW + e * 4 + q] = pk;
                }
            }
        }
    }
    __syncthreads();

    float t1[8] = {0, 0, 0, 0, 0, 0, 0, 0};
    float t2[8] = {0, 0, 0, 0, 0, 0, 0, 0};

    if (z < OUTD) {
        for (int y = 0; y < 4; ++y) {
            if (y0 + y >= OUTD) break;     // wave-uniform
            #pragma unroll
            for (int nt = 0; nt < 3; ++nt) {
                const int col = nt * 16 + n;
                const unsigned* bp = &xdw[(wv * 6 + y) * ROWDW + col * 4 + kq];
                f32x4 a0e = {0, 0, 0, 0}, a0o = {0, 0, 0, 0};   // h=0, even/odd chunk chains
                f32x4 a1e = {0, 0, 0, 0}, a1o = {0, 0, 0, 0};   // h=1
                #pragma unroll
                for (int kd = 0; kd < 3; ++kd) {
                    #pragma unroll
                    for (int kh = 0; kh < 3; ++kh) {
                        const int ch = kd * 3 + kh;
                        const unsigned* p = bp + (kd * 6 + kh) * ROWDW;
                        unsigned b0 = p[0], b1 = p[4], b2 = p[8], b3 = p[12];
                        v8s B = __builtin_bit_cast(v8s, (i32x4){(int)b0, (int)b1, (int)b2, (int)b3});
                        if (ch & 1) {
                            a0o = __builtin_amdgcn_mfma_f32_16x16x32_bf16(Al[0][ch], B, a0o, 0, 0, 0);
                            a0o = __builtin_amdgcn_mfma_f32_16x16x32_bf16(Ah[0][ch], B, a0o, 0, 0, 0);
                            a1o = __builtin_amdgcn_mfma_f32_16x16x32_bf16(Al[1][ch], B, a1o, 0, 0, 0);
                            a1o = __builtin_amdgcn_mfma_f32_16x16x32_bf16(Ah[1][ch], B, a1o, 0, 0, 0);
                        } else {
                            a0e = __builtin_amdgcn_mfma_f32_16x16x32_bf16(Al[0][ch], B, a0e, 0, 0, 0);
                            a0e = __builtin_amdgcn_mfma_f32_16x16x32_bf16(Ah[0][ch], B, a0e, 0, 0, 0);
                            a1e = __builtin_amdgcn_mfma_f32_16x16x32_bf16(Al[1][ch], B, a1e, 0, 0, 0);
                            a1e = __builtin_amdgcn_mfma_f32_16x16x32_bf16(Ah[1][ch], B, a1e, 0, 0, 0);
                        }
                    }
                }
                const bool cok = col < OUTD;
                #pragma unroll
                for (int h = 0; h < 2; ++h) {
                    #pragma unroll
                    for (int i = 0; i < 4; ++i) {
                        float a = h ? (a1e[i] + a1o[i]) : (a0e[i] + a0o[i]);
                        float v = a + bias_r[h * 4 + i];
                        float u = fminf(fmaxf(v + 3.0f, 0.0f), 6.0f);
                        float hs = v * u * (1.0f / 6.0f);
                        float hm = cok ? hs : 0.f;
                        t1[h * 4 + i] += hm;
                        t2[h * 4 + i] = fmaf(hm, hm, t2[h * 4 + i]);
                    }
                }
            }
        }
    }

    // ---- reduce over the 16 col-lanes (n); channel set is per-(kq,h,i).
    #pragma unroll
    for (int j = 0; j < 8; ++j) {
        #pragma unroll
        for (int k = 1; k < 16; k <<= 1) {
            t1[j] += __shfl_xor(t1[j], k, 64);
            t2[j] += __shfl_xor(t2[j], k, 64);
        }
    }
    if (n == 0) {
        #pragma unroll
        for (int h = 0; h < 2; ++h)
            #pragma unroll
            for (int i = 0; i < 4; ++i) {
                atomicAdd(&s1b[h * 16 + kq * 4 + i], t1[h * 4 + i]);
                atomicAdd(&s2b[h * 16 + kq * 4 + i], t2[h * 4 + i]);
            }
    }
    __syncthreads();
    if (tid < 32)       atomicAdd(&ws1[b * 32 + tid], s1b[tid]);
    else if (tid < 64)  atomicAdd(&ws2[b * 32 + (tid - 32)], s2b[tid - 32]);
}

__global__ __launch_bounds__(512) void gn_finalize(
    const float* __restrict__ ws1, const float* __restrict__ ws2,
    const float* __restrict__ gnw, const float* __restrict__ gnb,
    float* __restrict__ out)
{
    int tid = threadIdx.x;
    int c = tid & 31;
    float s1 = ws1[tid], s2 = ws2[tid];
    float g1 = s1, g2 = s2;
    #pragma unroll
    for (int k = 1; k < 8; k <<= 1) {
        g1 += __shfl_xor(g1, k, 64);
        g2 += __shfl_xor(g2, k, 64);
    }
    const float Nsp  = 46.0f * 46.0f * 46.0f;
    const float invN = 1.0f / (8.0f * Nsp);
    float mean = g1 * invN;
    float var  = fmaxf(g2 * invN - mean * mean, 0.0f);
    float rstd = rsqrtf(var + 1e-5f);
    float mc   = s1 * (1.0f / Nsp);
    out[tid] = (mc - mean) * rstd * gnw[c] + gnb[c];
}

extern "C" void kernel_launch(void* const* d_in, const int* in_sizes, int n_in,
                              void* d_out, int out_size, void* d_ws, size_t ws_size,
                              hipStream_t stream) {
    const float* x    = (const float*)d_in[0];
    const float* w    = (const float*)d_in[1];
    const float* bias = (const float*)d_in[2];
    const float* gnw  = (const float*)d_in[3];
    const float* gnb  = (const float*)d_in[4];
    float* out = (float*)d_out;
    float* ws1 = (float*)d_ws;
    float* ws2 = ws1 + 512;

    hipMemsetAsync(d_ws, 0, 1024 * sizeof(float), stream);
    conv_hs_mfma<<<dim3(16 * 12 * 12), dim3(256), 0, stream>>>(x, w, bias, ws1, ws2);
    gn_finalize<<<dim3(1), dim3(512), 0, stream>>>(ws1, ws2, gnw, gnb, out);
}

// Round 5
// 147.503 us; speedup vs baseline: 4.7480x; 1.0709x over previous
//
#include <hip/hip_runtime.h>

// Conv3d(8->32, k=3, VALID) + bias + HardSwish + GroupNorm(4) + mean pool.
// R5: (a) all 27 taps x 8 ci packed into 7 K=32 MFMA chunks (1 pad slot of 224),
// tap tau = 4t+j, ci = 2*kq + dword-parity -> 22% fewer MFMAs than R4's 9 chunks;
// (b) LDS bank swizzle dword = 4e + ((kq + 2*(e>>3))&3): injective per half-wave,
// kills R4's 7.3M 2-way conflict cycles; (c) weight hi/lo bf16 A-fragments
// precomputed once by pack_weights into ws (conv loads 28 coalesced dwordx4
// instead of 108 scalar loads + ~1.5k VALU per wave per block).

#define IN 48
#define IN2 2304
#define IN3 110592
#define OUTD 46
#define RS 200            // row stride in dwords (48*4 used + pad for masked overread)
#define NROW 36
#define WPK_OFF 1024      // dword offset of packed-weight table inside ws

typedef short v8s   __attribute__((ext_vector_type(8)));
typedef float f32x4 __attribute__((ext_vector_type(4)));
typedef int   i32x4 __attribute__((ext_vector_type(4)));

__device__ __forceinline__ unsigned short f2bf(float f) {
    unsigned u = __builtin_bit_cast(unsigned, f);
    return (unsigned short)((u + 0x7fffu + ((u >> 16) & 1u)) >> 16);   // RNE
}
__device__ __forceinline__ float bf2f(unsigned short h) {
    unsigned u = ((unsigned)h) << 16;
    return __builtin_bit_cast(float, u);
}

// One-time: build lane-exact A fragments. Layout: [hh=2h+hl][t 0..6][lane 0..63][4 dw]
// hl: 0 = hi bf16, 1 = lo bf16 (residual). tau = 4t+j; tau>=27 -> zero weight.
__global__ __launch_bounds__(256) void pack_weights(
    const float* __restrict__ w, unsigned* __restrict__ wpk)
{
    int gid = blockIdx.x * 256 + threadIdx.x;
    if (gid >= 1792) return;
    int lane = gid & 63;
    int rest = gid >> 6;
    int t  = rest % 7;
    int hh = rest / 7;
    int h  = hh >> 1, hl = hh & 1;
    int n  = lane & 15, kq = lane >> 4;
    int co = h * 16 + n;
    const float* wp = w + (co * 8 + 2 * kq) * 27;
    unsigned o[4];
    #pragma unroll
    for (int j = 0; j < 4; ++j) {
        int tau = 4 * t + j;
        if (tau >= 27) { o[j] = 0u; continue; }
        float w0 = wp[tau], w1 = wp[27 + tau];
        unsigned short b0 = f2bf(w0), b1 = f2bf(w1);
        if (hl) {
            b0 = f2bf(w0 - bf2f(b0));
            b1 = f2bf(w1 - bf2f(b1));
        }
        o[j] = ((unsigned)b1 << 16) | b0;
    }
    *(i32x4*)(wpk + ((hh * 7 + t) * 64 + lane) * 4) =
        (i32x4){(int)o[0], (int)o[1], (int)o[2], (int)o[3]};
}

__global__ __launch_bounds__(256, 2) void conv_hs_mfma(
    const float* __restrict__ x, const unsigned* __restrict__ wpk,
    const float* __restrict__ bias, float* __restrict__ ws1, float* __restrict__ ws2)
{
    __shared__ unsigned xdw[NROW * RS];   // 28.8 KB: [row 36][swizzled 4e+sw(kq,e)]
    __shared__ float s1b[32], s2b[32];

    const int tid  = threadIdx.x;
    const int lane = tid & 63;
    const int wv   = tid >> 6;          // wave id = z offset within tile
    const int n    = lane & 15;         // MFMA A-row (co) / B-col index
    const int kq   = lane >> 4;         // k-octet: ci pair {2kq, 2kq+1}

    const int blk = blockIdx.x;
    const int b   = blk / 144;
    const int r0  = blk - b * 144;
    const int zb  = r0 / 12;
    const int yb  = r0 - zb * 12;
    const int z0  = zb * 4, y0 = yb * 4;
    const int z   = z0 + wv;

    if (tid < 32) { s1b[tid] = 0.f; s2b[tid] = 0.f; }

    // A fragments: 28 coalesced 16B loads from the precomputed table.
    i32x4 Ah[2][7], Al[2][7];
    #pragma unroll
    for (int h = 0; h < 2; ++h)
        #pragma unroll
        for (int t = 0; t < 7; ++t) {
            Ah[h][t] = *(const i32x4*)(wpk + (((h * 2 + 0) * 7 + t) * 64 + lane) * 4);
            Al[h][t] = *(const i32x4*)(wpk + (((h * 2 + 1) * 7 + t) * 64 + lane) * 4);
        }

    // C/D layout: row(co) = kq*4 + i (+16h), col = n
    float bias_r[8];
    #pragma unroll
    for (int h = 0; h < 2; ++h)
        #pragma unroll
        for (int i = 0; i < 4; ++i)
            bias_r[h * 4 + i] = bias[h * 16 + kq * 4 + i];

    // ---- stage x tile, bf16 ci-pair packed + bank swizzle ----
    {
        const int q = tid & 3;
        const int e = tid >> 2;            // active e < 48
        if (e < 48) {
            const int sw = (q + 2 * (e >> 3)) & 3;
            const float* p0 = x + (b * 8 + 2 * q) * IN3 + e;
            const float* p1 = p0 + IN3;
            unsigned* dst = xdw + e * 4 + sw;
            #pragma unroll
            for (int zr = 0; zr < 6; ++zr) {
                const int gz = min(z0 + zr, IN - 1);
                #pragma unroll
                for (int yr = 0; yr < 6; ++yr) {
                    const int gy = min(y0 + yr, IN - 1);
                    const int off = gz * IN2 + gy * IN;
                    float f0 = p0[off], f1 = p1[off];
                    dst[(zr * 6 + yr) * RS] = ((unsigned)f2bf(f1) << 16) | f2bf(f0);
                }
            }
        }
    }
    __syncthreads();

    float t1[8] = {0, 0, 0, 0, 0, 0, 0, 0};
    float t2[8] = {0, 0, 0, 0, 0, 0, 0, 0};

    if (z < OUTD) {
        const int ymax = min(4, OUTD - y0);
        for (int y = 0; y < ymax; ++y) {
            const unsigned* yp = xdw + (wv * 6 + y) * RS;
            #pragma unroll
            for (int nt = 0; nt < 3; ++nt) {
                const int col = nt * 16 + n;
                const unsigned* pk[3];
                #pragma unroll
                for (int kw = 0; kw < 3; ++kw) {
                    const int e = col + kw;
                    pk[kw] = yp + e * 4 + ((kq + 2 * (e >> 3)) & 3);
                }
                f32x4 a0h = {0, 0, 0, 0}, a0l = {0, 0, 0, 0};
                f32x4 a1h = {0, 0, 0, 0}, a1l = {0, 0, 0, 0};
                #pragma unroll
                for (int t = 0; t < 7; ++t) {
                    unsigned bd[4];
                    #pragma unroll
                    for (int j = 0; j < 4; ++j) {
                        int tau = 4 * t + j; if (tau > 26) tau = 26;   // pad slot: A=0
                        const int kd = tau / 9, kh = (tau % 9) / 3, kw = tau % 3;
                        bd[j] = pk[kw][(kd * 6 + kh) * RS];
                    }
                    v8s B = __builtin_bit_cast(v8s, (i32x4){(int)bd[0], (int)bd[1], (int)bd[2], (int)bd[3]});
                    a0h = __builtin_amdgcn_mfma_f32_16x16x32_bf16(__builtin_bit_cast(v8s, Ah[0][t]), B, a0h, 0, 0, 0);
                    a0l = __builtin_amdgcn_mfma_f32_16x16x32_bf16(__builtin_bit_cast(v8s, Al[0][t]), B, a0l, 0, 0, 0);
                    a1h = __builtin_amdgcn_mfma_f32_16x16x32_bf16(__builtin_bit_cast(v8s, Ah[1][t]), B, a1h, 0, 0, 0);
                    a1l = __builtin_amdgcn_mfma_f32_16x16x32_bf16(__builtin_bit_cast(v8s, Al[1][t]), B, a1l, 0, 0, 0);
                }
                const bool cok = col < OUTD;
                #pragma unroll
                for (int h = 0; h < 2; ++h) {
                    #pragma unroll
                    for (int i = 0; i < 4; ++i) {
                        float ac = h ? (a1h[i] + a1l[i]) : (a0h[i] + a0l[i]);
                        float v = ac + bias_r[h * 4 + i];
                        float u = fminf(fmaxf(v + 3.0f, 0.0f), 6.0f);
                        float hs = v * u * (1.0f / 6.0f);
                        float hm = cok ? hs : 0.f;
                        t1[h * 4 + i] += hm;
                        t2[h * 4 + i] = fmaf(hm, hm, t2[h * 4 + i]);
                    }
                }
            }
        }
    }

    // reduce over the 16 col-lanes (n); channel set is per-(kq,h,i)
    #pragma unroll
    for (int j = 0; j < 8; ++j) {
        #pragma unroll
        for (int k = 1; k < 16; k <<= 1) {
            t1[j] += __shfl_xor(t1[j], k, 64);
            t2[j] += __shfl_xor(t2[j], k, 64);
        }
    }
    if (n == 0) {
        #pragma unroll
        for (int h = 0; h < 2; ++h)
            #pragma unroll
            for (int i = 0; i < 4; ++i) {
                atomicAdd(&s1b[h * 16 + kq * 4 + i], t1[h * 4 + i]);
                atomicAdd(&s2b[h * 16 + kq * 4 + i], t2[h * 4 + i]);
            }
    }
    __syncthreads();
    if (tid < 32)       atomicAdd(&ws1[b * 32 + tid], s1b[tid]);
    else if (tid < 64)  atomicAdd(&ws2[b * 32 + (tid - 32)], s2b[tid - 32]);
}

__global__ __launch_bounds__(512) void gn_finalize(
    const float* __restrict__ ws1, const float* __restrict__ ws2,
    const float* __restrict__ gnw, const float* __restrict__ gnb,
    float* __restrict__ out)
{
    int tid = threadIdx.x;
    int c = tid & 31;
    float s1 = ws1[tid], s2 = ws2[tid];
    float g1 = s1, g2 = s2;
    #pragma unroll
    for (int k = 1; k < 8; k <<= 1) {
        g1 += __shfl_xor(g1, k, 64);
        g2 += __shfl_xor(g2, k, 64);
    }
    const float Nsp  = 46.0f * 46.0f * 46.0f;
    const float invN = 1.0f / (8.0f * Nsp);
    float mean = g1 * invN;
    float var  = fmaxf(g2 * invN - mean * mean, 0.0f);
    float rstd = rsqrtf(var + 1e-5f);
    float mc   = s1 * (1.0f / Nsp);
    out[tid] = (mc - mean) * rstd * gnw[c] + gnb[c];
}

extern "C" void kernel_launch(void* const* d_in, const int* in_sizes, int n_in,
                              void* d_out, int out_size, void* d_ws, size_t ws_size,
                              hipStream_t stream) {
    const float* x    = (const float*)d_in[0];
    const float* w    = (const float*)d_in[1];
    const float* bias = (const float*)d_in[2];
    const float* gnw  = (const float*)d_in[3];
    const float* gnb  = (const float*)d_in[4];
    float* out = (float*)d_out;
    float* ws1 = (float*)d_ws;
    float* ws2 = ws1 + 512;
    unsigned* wpk = (unsigned*)d_ws + WPK_OFF;   // 14336 dwords

    hipMemsetAsync(d_ws, 0, 1024 * sizeof(float), stream);
    pack_weights<<<dim3(7), dim3(256), 0, stream>>>(w, wpk);
    conv_hs_mfma<<<dim3(16 * 12 * 12), dim3(256), 0, stream>>>(x, wpk, bias, ws1, ws2);
    gn_finalize<<<dim3(1), dim3(512), 0, stream>>>(ws1, ws2, gnw, gnb, out);
}